// Round 9
// baseline (280.755 us; speedup 1.0000x reference)
//
// R16: k_sum relocated INTO k_reduce. R15 lesson: fusing sum blocks into the
// gemm launch diluted gemm occupancy (88us ~= concatenation). Structural fact:
// k_reduce block bid consumes exactly S[bid], and k_sum has the same launch
// shape (256x256, block b -> S[b]) -> prepend the k_sum body VERBATIM into
// k_reduce (same mapping/order -> S bit-identical), consume the local value.
// Gemm returns to pure 512-block form (full 2 blocks/CU from t=0); fam zeroed
// by gemm block 0. All reduction orders preserved -> absmax 0.
// gemm body / k_sample / PRNG byte-identical to R14.
#include <hip/hip_runtime.h>
#include <stdint.h>

#define BATCH 256
#define NMAC  512
#define ROWF  128            // cms_prev * neur_prev
#define I_    32768
#define C_    32
#define N_    32
#define XROW  (NMAC * ROWF)  // 65536 floats per batch row
#define NCH   64             // split-K chunks (512 i each)

typedef float  f32x4  __attribute__((ext_vector_type(4)));
typedef __bf16 bf16x8 __attribute__((ext_vector_type(8)));

__device__ __forceinline__ uint32_t f2bf_rne(float f) {
    uint32_t u = __builtin_bit_cast(uint32_t, f);
    return (u + 0x7FFFu + ((u >> 16) & 1u)) >> 16;
}

// ---------------- gemm: part[chunk][b,c,n] (R14 body; fam zero at block 0) ---
// grid = 8 c-groups (4 c each) x 64 k-chunks (512 i each). 256 thr, 4 waves.
__global__ __launch_bounds__(256, 2) void k_gemm(const float* __restrict__ x,
                                                 const int* __restrict__ filt,
                                                 const float* __restrict__ w,
                                                 float* __restrict__ part,
                                                 float* __restrict__ fam) {
    __shared__ __align__(16) unsigned short afr[32 * 512];  // 32 KB: 16 rt x 2 part
    __shared__ __align__(16) unsigned short wfr[8 * 512];   //  8 KB: 8 ct (c x n-half)

    const int t  = threadIdx.x;
    if (blockIdx.x == 0 && t == 0) fam[0] = 0.f;  // stream-ordered before k_reduce
    const int l  = t & 63;
    const int wv = t >> 6;
    const int chunk = blockIdx.x & 63;
    const int c0 = (blockIdx.x >> 6) * 4;

    f32x4 acc[4][8];
#pragma unroll
    for (int bt = 0; bt < 4; ++bt)
#pragma unroll
        for (int ct = 0; ct < 8; ++ct) acc[bt][ct] = f32x4{0.f, 0.f, 0.f, 0.f};

    // A staging map: thread covers (row = rr*32 + (t>>3), k = (t&7)*4 .. +3)
    const int ar     = t >> 3;             // 0..31
    const int ai     = t & 7;              // float4 slot: k = ai*4+e
    const int a_quad = ai >> 1;            // (ai*4)>>3
    const int a_j    = (ai & 1) * 4;
    // W staging map
    const int wn = t & 31;
    const int wc = t >> 5;                 // 0..7

    for (int st = 0; st < 16; ++st) {
        const int ifull = chunk * 512 + st * 32;
        const int fidx  = filt[ifull >> 7];
        const int ioff  = ifull & 127;     // 0,32,64,96 — all 32 i's in one filter row
        const float* xs = x + (size_t)fidx * ROWF + ioff;

        // ---- stage A: 32 KB fp32 -> split bf16 frag-order LDS ----
#pragma unroll
        for (int rr = 0; rr < 8; ++rr) {
            int row = rr * 32 + ar;
            float4 v = *(const float4*)(xs + (size_t)row * XROW + ai * 4);
            uint32_t u0 = __builtin_bit_cast(uint32_t, v.x);
            uint32_t u1 = __builtin_bit_cast(uint32_t, v.y);
            uint32_t u2 = __builtin_bit_cast(uint32_t, v.z);
            uint32_t u3 = __builtin_bit_cast(uint32_t, v.w);
            // hi = truncate-to-bf16 (error absorbed by lo); lo = RNE bf16 of remainder
            float l0 = v.x - __builtin_bit_cast(float, u0 & 0xFFFF0000u);
            float l1 = v.y - __builtin_bit_cast(float, u1 & 0xFFFF0000u);
            float l2 = v.z - __builtin_bit_cast(float, u2 & 0xFFFF0000u);
            float l3 = v.w - __builtin_bit_cast(float, u3 & 0xFFFF0000u);
            uint2 hp, lp;
            hp.x = (u0 >> 16) | (u1 & 0xFFFF0000u);
            hp.y = (u2 >> 16) | (u3 & 0xFFFF0000u);
            lp.x = f2bf_rne(l0) | (f2bf_rne(l1) << 16);
            lp.y = f2bf_rne(l2) | (f2bf_rne(l3) << 16);
            int rt   = row >> 4;
            int lane = a_quad * 16 + (row & 15);
            int base = (rt * 2) * 512 + lane * 8 + a_j;
            *(uint2*)&afr[base]       = hp;          // part 0 (hi)
            *(uint2*)&afr[base + 512] = lp;          // part 1 (lo)
        }

        // ---- stage W: k-pair scalar loads, pack top-16s ({0,1} exact), frag order ----
#pragma unroll
        for (int q = 0; q < 8; ++q) {
            int sl  = wc + 8 * q;                    // 0..63 = (c, il-pair)
            int c   = sl >> 4;
            int il  = (sl & 15) * 2;                 // even k in [0,32)
            const float* wp = w + ((size_t)(c0 + c) * I_ + ifull + il) * N_ + wn;
            uint32_t u0 = __builtin_bit_cast(uint32_t, wp[0]);
            uint32_t u1 = __builtin_bit_cast(uint32_t, wp[N_]);
            uint32_t pk = (u0 >> 16) | (u1 & 0xFFFF0000u);
            int lane = (il >> 3) * 16 + (wn & 15);
            int ct   = c * 2 + (wn >> 4);
            *(uint32_t*)&wfr[ct * 512 + lane * 8 + (il & 7)] = pk;
        }
        __syncthreads();

        // ---- MFMA: 4 row-tiles x 8 (c,n)-tiles x 2 parts ----
        bf16x8 av[4][2];
#pragma unroll
        for (int bt = 0; bt < 4; ++bt)
#pragma unroll
            for (int p = 0; p < 2; ++p)
                av[bt][p] = *(const bf16x8*)&afr[((wv * 4 + bt) * 2 + p) * 512 + l * 8];
        bf16x8 bv[8];
#pragma unroll
        for (int ct = 0; ct < 8; ++ct)
            bv[ct] = *(const bf16x8*)&wfr[ct * 512 + l * 8];
#pragma unroll
        for (int bt = 0; bt < 4; ++bt)
#pragma unroll
            for (int ct = 0; ct < 8; ++ct) {
                acc[bt][ct] = __builtin_amdgcn_mfma_f32_16x16x32_bf16(av[bt][0], bv[ct], acc[bt][ct], 0, 0, 0);
                acc[bt][ct] = __builtin_amdgcn_mfma_f32_16x16x32_bf16(av[bt][1], bv[ct], acc[bt][ct], 0, 0, 0);
            }
        __syncthreads();
    }

    // ---- epilogue: split-K stores (D col = lane&15, row = (lane>>4)*4 + reg) ----
    const int quad = l >> 4, n15 = l & 15;
    float* dst = part + (size_t)chunk * (BATCH * C_ * N_);
#pragma unroll
    for (int bt = 0; bt < 4; ++bt) {
#pragma unroll
        for (int ct = 0; ct < 8; ++ct) {
            int c = c0 + (ct >> 1);
            int n = (ct & 1) * 16 + n15;
#pragma unroll
            for (int r = 0; r < 4; ++r) {
                int b = (wv * 4 + bt) * 16 + quad * 4 + r;
                dst[((size_t)b * C_ + c) * N_ + n] = acc[bt][ct][r];
            }
        }
    }
}

// ---------------- reduce2: k_sum body (verbatim, b=bid) + split-K reduce -----
// Block bid: (1) S[bid] via the exact k_sum mapping/order -> bit-identical;
// (2) raw rows [bid*32, bid*32+32) = sum_ch part[ch]; fam partial with local Sb.
__global__ __launch_bounds__(256) void k_reduce(const float* __restrict__ x,
                                                const int* __restrict__ filt,
                                                const float* __restrict__ part,
                                                float* __restrict__ S,
                                                float* __restrict__ raw,
                                                float* __restrict__ fam) {
    const int b = blockIdx.x;
    const int t = threadIdx.x;
    __shared__ float red[4];

    // ---- phase 1: k_sum body (R14 verbatim) ----
    {
        const float* xb = x + (size_t)b * XROW;
        float s = 0.f;
        for (int it = 0; it < 32; ++it) {
            int idx4 = it * 256 + t;           // 8192 float4 in gathered row
            int f = idx4 >> 5;
            int j4 = idx4 & 31;
            float4 v = *(const float4*)(xb + (size_t)filt[f] * ROWF + j4 * 4);
            s += v.x + v.y + v.z + v.w;
        }
        for (int o = 32; o > 0; o >>= 1) s += __shfl_down(s, o, 64);
        if ((t & 63) == 0) red[t >> 6] = s;
        __syncthreads();
        if (t == 0) S[b] = red[0] + red[1] + red[2] + red[3];
    }
    // all threads compute Sb identically (same add order as S[b] above)
    const float Sb = red[0] + red[1] + red[2] + red[3];
    __syncthreads();                        // red[] reused by fam phase below

    // ---- phase 2: split-K reduce + fused familiarity (R14 body; S -> Sb) ----
    const int i4 = b * 256 + t;             // 65536 float4; rows r = i4>>3 have r>>5 == b
    const f32x4* p = (const f32x4*)part;
    f32x4 sv = f32x4{0.f, 0.f, 0.f, 0.f};
#pragma unroll 8
    for (int ch = 0; ch < NCH; ++ch) sv += p[(size_t)ch * 65536 + i4];
    ((f32x4*)raw)[i4] = sv;
    float m = fmaxf(fmaxf(sv[0], sv[1]), fmaxf(sv[2], sv[3]));
    m = fmaxf(m, __shfl_xor(m, 1, 64));
    m = fmaxf(m, __shfl_xor(m, 2, 64));
    m = fmaxf(m, __shfl_xor(m, 4, 64));
    float v = ((i4 & 7) == 0) ? (m / Sb) : 0.f;   // divide after max: monotone-exact
    for (int o = 32; o > 0; o >>= 1) v += __shfl_down(v, o, 64);
    if ((t & 63) == 0) red[t >> 6] = v;
    __syncthreads();
    if (t == 0) atomicAdd(fam, red[0] + red[1] + red[2] + red[3]);
}

// ---------------- standalone k_sum (fallback path only; R14 verbatim) --------
__global__ __launch_bounds__(256) void k_sum(const float* __restrict__ x,
                                             const int* __restrict__ filt,
                                             float* __restrict__ S,
                                             float* __restrict__ fam) {
    const int b = blockIdx.x;
    const int t = threadIdx.x;
    if (b == 0 && t == 0) fam[0] = 0.f;
    const float* xb = x + (size_t)b * XROW;
    float s = 0.f;
    for (int it = 0; it < 32; ++it) {
        int idx4 = it * 256 + t;
        int f = idx4 >> 5;
        int j4 = idx4 & 31;
        float4 v = *(const float4*)(xb + (size_t)filt[f] * ROWF + j4 * 4);
        s += v.x + v.y + v.z + v.w;
    }
    for (int o = 32; o > 0; o >>= 1) s += __shfl_down(s, o, 64);
    __shared__ float red[4];
    if ((t & 63) == 0) red[t >> 6] = s;
    __syncthreads();
    if (t == 0) S[b] = red[0] + red[1] + red[2] + red[3];
}

// ---------------- legacy gemm (atomic fallback only; R9 body) ----------------
__global__ __launch_bounds__(256, 2) void k_gemm_fb(const float* __restrict__ x,
                                                    const int* __restrict__ filt,
                                                    const float* __restrict__ w,
                                                    float* __restrict__ raw) {
    __shared__ __align__(16) unsigned short afr[32 * 512];
    __shared__ __align__(16) unsigned short wfr[8 * 512];

    const int t  = threadIdx.x;
    const int l  = t & 63;
    const int wv = t >> 6;
    const int chunk = blockIdx.x & 63;
    const int c0 = (blockIdx.x >> 6) * 4;

    f32x4 acc[4][8];
#pragma unroll
    for (int bt = 0; bt < 4; ++bt)
#pragma unroll
        for (int ct = 0; ct < 8; ++ct) acc[bt][ct] = f32x4{0.f, 0.f, 0.f, 0.f};

    const int ar     = t >> 3;
    const int ai     = t & 7;
    const int a_quad = ai >> 1;
    const int a_j    = (ai & 1) * 4;
    const int wn = t & 31;
    const int wc = t >> 5;

    for (int st = 0; st < 16; ++st) {
        const int ifull = chunk * 512 + st * 32;
        const int fidx  = filt[ifull >> 7];
        const int ioff  = ifull & 127;
        const float* xs = x + (size_t)fidx * ROWF + ioff;

#pragma unroll
        for (int rr = 0; rr < 8; ++rr) {
            int row = rr * 32 + ar;
            float4 v = *(const float4*)(xs + (size_t)row * XROW + ai * 4);
            uint32_t u0 = __builtin_bit_cast(uint32_t, v.x);
            uint32_t u1 = __builtin_bit_cast(uint32_t, v.y);
            uint32_t u2 = __builtin_bit_cast(uint32_t, v.z);
            uint32_t u3 = __builtin_bit_cast(uint32_t, v.w);
            float l0 = v.x - __builtin_bit_cast(float, u0 & 0xFFFF0000u);
            float l1 = v.y - __builtin_bit_cast(float, u1 & 0xFFFF0000u);
            float l2 = v.z - __builtin_bit_cast(float, u2 & 0xFFFF0000u);
            float l3 = v.w - __builtin_bit_cast(float, u3 & 0xFFFF0000u);
            uint2 hp, lp;
            hp.x = (u0 >> 16) | (u1 & 0xFFFF0000u);
            hp.y = (u2 >> 16) | (u3 & 0xFFFF0000u);
            lp.x = f2bf_rne(l0) | (f2bf_rne(l1) << 16);
            lp.y = f2bf_rne(l2) | (f2bf_rne(l3) << 16);
            int rt   = row >> 4;
            int lane = a_quad * 16 + (row & 15);
            int base = (rt * 2) * 512 + lane * 8 + a_j;
            *(uint2*)&afr[base]       = hp;
            *(uint2*)&afr[base + 512] = lp;
        }
#pragma unroll
        for (int q = 0; q < 8; ++q) {
            int sl  = wc + 8 * q;
            int c   = sl >> 4;
            int il  = (sl & 15) * 2;
            const float* wp = w + ((size_t)(c0 + c) * I_ + ifull + il) * N_ + wn;
            uint32_t u0 = __builtin_bit_cast(uint32_t, wp[0]);
            uint32_t u1 = __builtin_bit_cast(uint32_t, wp[N_]);
            uint32_t pk = (u0 >> 16) | (u1 & 0xFFFF0000u);
            int lane = (il >> 3) * 16 + (wn & 15);
            int ct   = c * 2 + (wn >> 4);
            *(uint32_t*)&wfr[ct * 512 + lane * 8 + (il & 7)] = pk;
        }
        __syncthreads();

        bf16x8 av[4][2];
#pragma unroll
        for (int bt = 0; bt < 4; ++bt)
#pragma unroll
            for (int p = 0; p < 2; ++p)
                av[bt][p] = *(const bf16x8*)&afr[((wv * 4 + bt) * 2 + p) * 512 + l * 8];
        bf16x8 bv[8];
#pragma unroll
        for (int ct = 0; ct < 8; ++ct)
            bv[ct] = *(const bf16x8*)&wfr[ct * 512 + l * 8];
#pragma unroll
        for (int bt = 0; bt < 4; ++bt)
#pragma unroll
            for (int ct = 0; ct < 8; ++ct) {
                acc[bt][ct] = __builtin_amdgcn_mfma_f32_16x16x32_bf16(av[bt][0], bv[ct], acc[bt][ct], 0, 0, 0);
                acc[bt][ct] = __builtin_amdgcn_mfma_f32_16x16x32_bf16(av[bt][1], bv[ct], acc[bt][ct], 0, 0, 0);
            }
        __syncthreads();
    }

    const int quad = l >> 4, n15 = l & 15;
#pragma unroll
    for (int bt = 0; bt < 4; ++bt)
#pragma unroll
        for (int ct = 0; ct < 8; ++ct) {
            int c = c0 + (ct >> 1);
            int n = (ct & 1) * 16 + n15;
#pragma unroll
            for (int r = 0; r < 4; ++r) {
                int b = (wv * 4 + bt) * 16 + quad * 4 + r;
                atomicAdd(&raw[((size_t)b * C_ + c) * N_ + n], acc[bt][ct][r]);
            }
        }
}

// ---------------- familiarity (atomic-fallback path only) --------------------
__global__ __launch_bounds__(256) void k_fam(const float* __restrict__ raw,
                                             const float* __restrict__ S,
                                             float* __restrict__ fam) {
    int r = blockIdx.x * 256 + threadIdx.x;            // 8192 rows
    const float4* ap = (const float4*)(raw + (size_t)r * N_);
    float m = -3.0e38f;
#pragma unroll
    for (int q = 0; q < 8; ++q) {
        float4 v = ap[q];
        m = fmaxf(m, fmaxf(fmaxf(v.x, v.y), fmaxf(v.z, v.w)));
    }
    m = m / S[r >> 5];
    for (int o = 32; o > 0; o >>= 1) m += __shfl_down(m, o, 64);
    __shared__ float red[4];
    if ((threadIdx.x & 63) == 0) red[threadIdx.x >> 6] = m;
    __syncthreads();
    if (threadIdx.x == 0) atomicAdd(fam, red[0] + red[1] + red[2] + red[3]);
}

// ---------------- Threefry-2x32-20 core (unchanged) ----------------
__device__ __forceinline__ uint32_t rotl32(uint32_t x, uint32_t r) {
    return (x << r) | (x >> (32u - r));
}
__device__ __forceinline__ void threefry(uint32_t k0, uint32_t k1,
                                         uint32_t x0, uint32_t x1,
                                         uint32_t& o0, uint32_t& o1) {
    uint32_t ks2 = k0 ^ k1 ^ 0x1BD11BDAu;
    x0 += k0; x1 += k1;
    x0 += x1; x1 = rotl32(x1, 13); x1 ^= x0;
    x0 += x1; x1 = rotl32(x1, 15); x1 ^= x0;
    x0 += x1; x1 = rotl32(x1, 26); x1 ^= x0;
    x0 += x1; x1 = rotl32(x1, 6);  x1 ^= x0;
    x0 += k1; x1 += ks2 + 1u;
    x0 += x1; x1 = rotl32(x1, 17); x1 ^= x0;
    x0 += x1; x1 = rotl32(x1, 29); x1 ^= x0;
    x0 += x1; x1 = rotl32(x1, 16); x1 ^= x0;
    x0 += x1; x1 = rotl32(x1, 24); x1 ^= x0;
    x0 += ks2; x1 += k0 + 2u;
    x0 += x1; x1 = rotl32(x1, 13); x1 ^= x0;
    x0 += x1; x1 = rotl32(x1, 15); x1 ^= x0;
    x0 += x1; x1 = rotl32(x1, 26); x1 ^= x0;
    x0 += x1; x1 = rotl32(x1, 6);  x1 ^= x0;
    x0 += k0; x1 += k1 + 3u;
    x0 += x1; x1 = rotl32(x1, 17); x1 ^= x0;
    x0 += x1; x1 = rotl32(x1, 29); x1 ^= x0;
    x0 += x1; x1 = rotl32(x1, 16); x1 ^= x0;
    x0 += x1; x1 = rotl32(x1, 24); x1 ^= x0;
    x0 += k1; x1 += ks2 + 4u;
    x0 += x1; x1 = rotl32(x1, 13); x1 ^= x0;
    x0 += x1; x1 = rotl32(x1, 15); x1 ^= x0;
    x0 += x1; x1 = rotl32(x1, 26); x1 ^= x0;
    x0 += x1; x1 = rotl32(x1, 6);  x1 ^= x0;
    x0 += ks2; x1 += k0 + 5u;
    o0 = x0; o1 = x1;
}

__device__ __forceinline__ float gumbel_of(uint32_t bits) {
    uint32_t fb = (bits >> 9) | 0x3F800000u;
    float f = __builtin_bit_cast(float, fb) - 1.0f;
    float u = f + 1.17549435e-38f;                     // == max(tiny, f*(1-tiny)+tiny)
    return -logf(-logf(u));
}

// ---------------- sample (unchanged: JAX partitionable threefry layout) ------
__global__ __launch_bounds__(256) void k_sample(const float* __restrict__ raw,
                                                const float* __restrict__ S,
                                                const float* __restrict__ fam,
                                                int* __restrict__ out) {
    int r0 = blockIdx.x * 256 + threadIdx.x;           // 0..4095
    int r1 = r0 + 4096;
    float avg  = fam[0] * (1.0f / 8192.0f);
    float temp = 1.0f / (avg + 1e-4f) - 1.0f;
    float sA = S[r0 >> 5], sB = S[r1 >> 5];
    const float* apA = raw + (size_t)r0 * N_;
    const float* apB = raw + (size_t)r1 * N_;

    float bestA = -3.4e38f, bestB = -3.4e38f;
    int biA = 0, biB = 0;
    for (int n = 0; n < 32; ++n) {
        uint32_t iA = (uint32_t)(r0 * 32 + n);
        uint32_t iB = (uint32_t)(r1 * 32 + n);
        uint32_t a0, a1, b0, b1;
        threefry(0u, 42u, 0u, iA, a0, a1);
        threefry(0u, 42u, 0u, iB, b0, b1);
        float vA = (apA[n] / sA) / temp + gumbel_of(a0 ^ a1);
        float vB = (apB[n] / sB) / temp + gumbel_of(b0 ^ b1);
        if (vA > bestA) { bestA = vA; biA = n; }
        if (vB > bestB) { bestB = vB; biB = n; }
    }
    int4* opA = (int4*)(out + (size_t)r0 * N_);
    int4* opB = (int4*)(out + (size_t)r1 * N_);
#pragma unroll
    for (int q = 0; q < 8; ++q) {
        int4 a, b;
        a.x = (q * 4 + 0) == biA; a.y = (q * 4 + 1) == biA;
        a.z = (q * 4 + 2) == biA; a.w = (q * 4 + 3) == biA;
        b.x = (q * 4 + 0) == biB; b.y = (q * 4 + 1) == biB;
        b.z = (q * 4 + 2) == biB; b.w = (q * 4 + 3) == biB;
        opA[q] = a; opB[q] = b;
    }
}

extern "C" void kernel_launch(void* const* d_in, const int* in_sizes, int n_in,
                              void* d_out, int out_size, void* d_ws, size_t ws_size,
                              hipStream_t stream) {
    const float* x    = (const float*)d_in[0];
    const int*   filt = (const int*)d_in[1];
    const float* w    = (const float*)d_in[2];
    int* out = (int*)d_out;

    char* ws = (char*)d_ws;
    float* raw  = (float*)ws;                          // 1 MB  (256*32*32 fp32)
    float* fam  = (float*)(ws + (1 << 20));            // 4 B
    float* S    = (float*)(ws + (1 << 20) + 128);      // 1 KB
    float* part = (float*)(ws + (2u << 20));           // 64 MB split-K partials

    const size_t need = (2u << 20) + (size_t)NCH * (BATCH * C_ * N_) * sizeof(float);
    const int use_part = (ws_size >= need) ? 1 : 0;

    if (use_part) {
        // fam zeroed by k_gemm block 0; S computed inside k_reduce (bit-identical body)
        hipLaunchKernelGGL(k_gemm,   dim3(512), dim3(256), 0, stream, x, filt, w, part, fam);
        hipLaunchKernelGGL(k_reduce, dim3(256), dim3(256), 0, stream, x, filt, part, S, raw, fam);
        hipLaunchKernelGGL(k_sample, dim3(16),  dim3(256), 0, stream, raw, S, fam, out);
    } else {
        hipMemsetAsync(ws, 0, (1 << 20) + 128, stream);          // raw + fam (atomic path)
        hipLaunchKernelGGL(k_sum,    dim3(256), dim3(256), 0, stream, x, filt, S, fam);
        hipLaunchKernelGGL(k_gemm_fb, dim3(512), dim3(256), 0, stream, x, filt, w, raw);
        hipLaunchKernelGGL(k_fam,    dim3(32),  dim3(256), 0, stream, raw, S, fam);
        hipLaunchKernelGGL(k_sample, dim3(16),  dim3(256), 0, stream, raw, S, fam, out);
    }
}

// Round 10
// 277.831 us; speedup vs baseline: 1.0105x; 1.0105x over previous
//
// R17 = R15 byte-identical (session-best verified: 278.6us). Final artifact.
// Plateau evidence: R14 278.9 / R15 278.6 / R16 280.8 (±1% noise band).
// Decomposition: ~158us harness poison fills @85% HBM peak (roofline, fixed) +
// ~86us fused sum+gemm (register-pinned local optimum; survived 7 structural
// attacks: R8 wide-block spill, R10 async-DMA null, R11 batch-split +W-HBM,
// R12 C-split +A-restage, R13 W-bitmask null, R15/R16 fusion variants) +
// ~20us reduce + ~3us sample + launch gaps.
#include <hip/hip_runtime.h>
#include <stdint.h>

#define BATCH 256
#define NMAC  512
#define ROWF  128            // cms_prev * neur_prev
#define I_    32768
#define C_    32
#define N_    32
#define XROW  (NMAC * ROWF)  // 65536 floats per batch row
#define NCH   64             // split-K chunks (512 i each)

typedef float  f32x4  __attribute__((ext_vector_type(4)));
typedef __bf16 bf16x8 __attribute__((ext_vector_type(8)));

__device__ __forceinline__ uint32_t f2bf_rne(float f) {
    uint32_t u = __builtin_bit_cast(uint32_t, f);
    return (u + 0x7FFFu + ((u >> 16) & 1u)) >> 16;
}

// ---------------- fused: blocks 0..255 = k_sum body, 256..767 = gemm body ----
__global__ __launch_bounds__(256, 2) void k_fused(const float* __restrict__ x,
                                                  const int* __restrict__ filt,
                                                  const float* __restrict__ w,
                                                  float* __restrict__ S,
                                                  float* __restrict__ fam,
                                                  float* __restrict__ part) {
    __shared__ __align__(16) unsigned short afr[32 * 512];  // 32 KB (gemm)
    __shared__ __align__(16) unsigned short wfr[8 * 512];   //  8 KB (gemm)
    __shared__ float red[4];                                // (sum path)

    const int t = threadIdx.x;

    if (blockIdx.x < 256) {
        // ---------------- k_sum body (b = blockIdx.x) ----------
        const int b = blockIdx.x;
        if (b == 0 && t == 0) fam[0] = 0.f;    // replaces hipMemsetAsync
        const float* xb = x + (size_t)b * XROW;
        float s = 0.f;
        for (int it = 0; it < 32; ++it) {
            int idx4 = it * 256 + t;           // 8192 float4 in gathered row
            int f = idx4 >> 5;
            int j4 = idx4 & 31;
            float4 v = *(const float4*)(xb + (size_t)filt[f] * ROWF + j4 * 4);
            s += v.x + v.y + v.z + v.w;
        }
        for (int o = 32; o > 0; o >>= 1) s += __shfl_down(s, o, 64);
        if ((t & 63) == 0) red[t >> 6] = s;
        __syncthreads();
        if (t == 0) S[b] = red[0] + red[1] + red[2] + red[3];
        return;
    }

    // ---------------- gemm body (bid' = blockIdx.x - 256) ------
    const int bid = blockIdx.x - 256;
    const int l  = t & 63;
    const int wv = t >> 6;
    const int chunk = bid & 63;
    const int c0 = (bid >> 6) * 4;

    f32x4 acc[4][8];
#pragma unroll
    for (int bt = 0; bt < 4; ++bt)
#pragma unroll
        for (int ct = 0; ct < 8; ++ct) acc[bt][ct] = f32x4{0.f, 0.f, 0.f, 0.f};

    // A staging map: thread covers (row = rr*32 + (t>>3), k = (t&7)*4 .. +3)
    const int ar     = t >> 3;             // 0..31
    const int ai     = t & 7;              // float4 slot: k = ai*4+e
    const int a_quad = ai >> 1;            // (ai*4)>>3
    const int a_j    = (ai & 1) * 4;
    // W staging map
    const int wn = t & 31;
    const int wc = t >> 5;                 // 0..7

    for (int st = 0; st < 16; ++st) {
        const int ifull = chunk * 512 + st * 32;
        const int fidx  = filt[ifull >> 7];
        const int ioff  = ifull & 127;     // 0,32,64,96 — all 32 i's in one filter row
        const float* xs = x + (size_t)fidx * ROWF + ioff;

        // ---- stage A: 32 KB fp32 -> split bf16 frag-order LDS ----
#pragma unroll
        for (int rr = 0; rr < 8; ++rr) {
            int row = rr * 32 + ar;
            float4 v = *(const float4*)(xs + (size_t)row * XROW + ai * 4);
            uint32_t u0 = __builtin_bit_cast(uint32_t, v.x);
            uint32_t u1 = __builtin_bit_cast(uint32_t, v.y);
            uint32_t u2 = __builtin_bit_cast(uint32_t, v.z);
            uint32_t u3 = __builtin_bit_cast(uint32_t, v.w);
            // hi = truncate-to-bf16 (error absorbed by lo); lo = RNE bf16 of remainder
            float l0 = v.x - __builtin_bit_cast(float, u0 & 0xFFFF0000u);
            float l1 = v.y - __builtin_bit_cast(float, u1 & 0xFFFF0000u);
            float l2 = v.z - __builtin_bit_cast(float, u2 & 0xFFFF0000u);
            float l3 = v.w - __builtin_bit_cast(float, u3 & 0xFFFF0000u);
            uint2 hp, lp;
            hp.x = (u0 >> 16) | (u1 & 0xFFFF0000u);
            hp.y = (u2 >> 16) | (u3 & 0xFFFF0000u);
            lp.x = f2bf_rne(l0) | (f2bf_rne(l1) << 16);
            lp.y = f2bf_rne(l2) | (f2bf_rne(l3) << 16);
            int rt   = row >> 4;
            int lane = a_quad * 16 + (row & 15);
            int base = (rt * 2) * 512 + lane * 8 + a_j;
            *(uint2*)&afr[base]       = hp;          // part 0 (hi)
            *(uint2*)&afr[base + 512] = lp;          // part 1 (lo)
        }

        // ---- stage W: k-pair scalar loads, pack top-16s ({0,1} exact), frag order ----
#pragma unroll
        for (int q = 0; q < 8; ++q) {
            int sl  = wc + 8 * q;                    // 0..63 = (c, il-pair)
            int c   = sl >> 4;
            int il  = (sl & 15) * 2;                 // even k in [0,32)
            const float* wp = w + ((size_t)(c0 + c) * I_ + ifull + il) * N_ + wn;
            uint32_t u0 = __builtin_bit_cast(uint32_t, wp[0]);
            uint32_t u1 = __builtin_bit_cast(uint32_t, wp[N_]);
            uint32_t pk = (u0 >> 16) | (u1 & 0xFFFF0000u);
            int lane = (il >> 3) * 16 + (wn & 15);
            int ct   = c * 2 + (wn >> 4);
            *(uint32_t*)&wfr[ct * 512 + lane * 8 + (il & 7)] = pk;
        }
        __syncthreads();

        // ---- MFMA: 4 row-tiles x 8 (c,n)-tiles x 2 parts ----
        bf16x8 av[4][2];
#pragma unroll
        for (int bt = 0; bt < 4; ++bt)
#pragma unroll
            for (int p = 0; p < 2; ++p)
                av[bt][p] = *(const bf16x8*)&afr[((wv * 4 + bt) * 2 + p) * 512 + l * 8];
        bf16x8 bv[8];
#pragma unroll
        for (int ct = 0; ct < 8; ++ct)
            bv[ct] = *(const bf16x8*)&wfr[ct * 512 + l * 8];
#pragma unroll
        for (int bt = 0; bt < 4; ++bt)
#pragma unroll
            for (int ct = 0; ct < 8; ++ct) {
                acc[bt][ct] = __builtin_amdgcn_mfma_f32_16x16x32_bf16(av[bt][0], bv[ct], acc[bt][ct], 0, 0, 0);
                acc[bt][ct] = __builtin_amdgcn_mfma_f32_16x16x32_bf16(av[bt][1], bv[ct], acc[bt][ct], 0, 0, 0);
            }
        __syncthreads();
    }

    // ---- epilogue: D col = lane&15, row = (lane>>4)*4 + reg ----
    const int quad = l >> 4, n15 = l & 15;
    float* dst = part + (size_t)chunk * (BATCH * C_ * N_);
#pragma unroll
    for (int bt = 0; bt < 4; ++bt) {
#pragma unroll
        for (int ct = 0; ct < 8; ++ct) {
            int c = c0 + (ct >> 1);
            int n = (ct & 1) * 16 + n15;
#pragma unroll
            for (int r = 0; r < 4; ++r) {
                int b = (wv * 4 + bt) * 16 + quad * 4 + r;
                dst[((size_t)b * C_ + c) * N_ + n] = acc[bt][ct][r];
            }
        }
    }
}

// ---------------- standalone k_sum (fallback path only) --------
__global__ __launch_bounds__(256) void k_sum(const float* __restrict__ x,
                                             const int* __restrict__ filt,
                                             float* __restrict__ S,
                                             float* __restrict__ fam) {
    const int b = blockIdx.x;
    const int t = threadIdx.x;
    if (b == 0 && t == 0) fam[0] = 0.f;
    const float* xb = x + (size_t)b * XROW;
    float s = 0.f;
    for (int it = 0; it < 32; ++it) {
        int idx4 = it * 256 + t;
        int f = idx4 >> 5;
        int j4 = idx4 & 31;
        float4 v = *(const float4*)(xb + (size_t)filt[f] * ROWF + j4 * 4);
        s += v.x + v.y + v.z + v.w;
    }
    for (int o = 32; o > 0; o >>= 1) s += __shfl_down(s, o, 64);
    __shared__ float red[4];
    if ((t & 63) == 0) red[t >> 6] = s;
    __syncthreads();
    if (t == 0) S[b] = red[0] + red[1] + red[2] + red[3];
}

// ---------------- legacy gemm (atomic fallback only; R9 body) ----------------
__global__ __launch_bounds__(256, 2) void k_gemm_fb(const float* __restrict__ x,
                                                    const int* __restrict__ filt,
                                                    const float* __restrict__ w,
                                                    float* __restrict__ raw) {
    __shared__ __align__(16) unsigned short afr[32 * 512];
    __shared__ __align__(16) unsigned short wfr[8 * 512];

    const int t  = threadIdx.x;
    const int l  = t & 63;
    const int wv = t >> 6;
    const int chunk = blockIdx.x & 63;
    const int c0 = (blockIdx.x >> 6) * 4;

    f32x4 acc[4][8];
#pragma unroll
    for (int bt = 0; bt < 4; ++bt)
#pragma unroll
        for (int ct = 0; ct < 8; ++ct) acc[bt][ct] = f32x4{0.f, 0.f, 0.f, 0.f};

    const int ar     = t >> 3;
    const int ai     = t & 7;
    const int a_quad = ai >> 1;
    const int a_j    = (ai & 1) * 4;
    const int wn = t & 31;
    const int wc = t >> 5;

    for (int st = 0; st < 16; ++st) {
        const int ifull = chunk * 512 + st * 32;
        const int fidx  = filt[ifull >> 7];
        const int ioff  = ifull & 127;
        const float* xs = x + (size_t)fidx * ROWF + ioff;

#pragma unroll
        for (int rr = 0; rr < 8; ++rr) {
            int row = rr * 32 + ar;
            float4 v = *(const float4*)(xs + (size_t)row * XROW + ai * 4);
            uint32_t u0 = __builtin_bit_cast(uint32_t, v.x);
            uint32_t u1 = __builtin_bit_cast(uint32_t, v.y);
            uint32_t u2 = __builtin_bit_cast(uint32_t, v.z);
            uint32_t u3 = __builtin_bit_cast(uint32_t, v.w);
            float l0 = v.x - __builtin_bit_cast(float, u0 & 0xFFFF0000u);
            float l1 = v.y - __builtin_bit_cast(float, u1 & 0xFFFF0000u);
            float l2 = v.z - __builtin_bit_cast(float, u2 & 0xFFFF0000u);
            float l3 = v.w - __builtin_bit_cast(float, u3 & 0xFFFF0000u);
            uint2 hp, lp;
            hp.x = (u0 >> 16) | (u1 & 0xFFFF0000u);
            hp.y = (u2 >> 16) | (u3 & 0xFFFF0000u);
            lp.x = f2bf_rne(l0) | (f2bf_rne(l1) << 16);
            lp.y = f2bf_rne(l2) | (f2bf_rne(l3) << 16);
            int rt   = row >> 4;
            int lane = a_quad * 16 + (row & 15);
            int base = (rt * 2) * 512 + lane * 8 + a_j;
            *(uint2*)&afr[base]       = hp;
            *(uint2*)&afr[base + 512] = lp;
        }
#pragma unroll
        for (int q = 0; q < 8; ++q) {
            int sl  = wc + 8 * q;
            int c   = sl >> 4;
            int il  = (sl & 15) * 2;
            const float* wp = w + ((size_t)(c0 + c) * I_ + ifull + il) * N_ + wn;
            uint32_t u0 = __builtin_bit_cast(uint32_t, wp[0]);
            uint32_t u1 = __builtin_bit_cast(uint32_t, wp[N_]);
            uint32_t pk = (u0 >> 16) | (u1 & 0xFFFF0000u);
            int lane = (il >> 3) * 16 + (wn & 15);
            int ct   = c * 2 + (wn >> 4);
            *(uint32_t*)&wfr[ct * 512 + lane * 8 + (il & 7)] = pk;
        }
        __syncthreads();

        bf16x8 av[4][2];
#pragma unroll
        for (int bt = 0; bt < 4; ++bt)
#pragma unroll
            for (int p = 0; p < 2; ++p)
                av[bt][p] = *(const bf16x8*)&afr[((wv * 4 + bt) * 2 + p) * 512 + l * 8];
        bf16x8 bv[8];
#pragma unroll
        for (int ct = 0; ct < 8; ++ct)
            bv[ct] = *(const bf16x8*)&wfr[ct * 512 + l * 8];
#pragma unroll
        for (int bt = 0; bt < 4; ++bt)
#pragma unroll
            for (int ct = 0; ct < 8; ++ct) {
                acc[bt][ct] = __builtin_amdgcn_mfma_f32_16x16x32_bf16(av[bt][0], bv[ct], acc[bt][ct], 0, 0, 0);
                acc[bt][ct] = __builtin_amdgcn_mfma_f32_16x16x32_bf16(av[bt][1], bv[ct], acc[bt][ct], 0, 0, 0);
            }
        __syncthreads();
    }

    const int quad = l >> 4, n15 = l & 15;
#pragma unroll
    for (int bt = 0; bt < 4; ++bt)
#pragma unroll
        for (int ct = 0; ct < 8; ++ct) {
            int c = c0 + (ct >> 1);
            int n = (ct & 1) * 16 + n15;
#pragma unroll
            for (int r = 0; r < 4; ++r) {
                int b = (wv * 4 + bt) * 16 + quad * 4 + r;
                atomicAdd(&raw[((size_t)b * C_ + c) * N_ + n], acc[bt][ct][r]);
            }
        }
}

// ---------------- split-K reduce + fused familiarity ----------
__global__ __launch_bounds__(256) void k_reduce(const float* __restrict__ part,
                                                const float* __restrict__ S,
                                                float* __restrict__ raw,
                                                float* __restrict__ fam) {
    const int i4 = blockIdx.x * 256 + threadIdx.x;     // 65536 float4
    const f32x4* p = (const f32x4*)part;
    f32x4 s = f32x4{0.f, 0.f, 0.f, 0.f};
#pragma unroll 8
    for (int ch = 0; ch < NCH; ++ch) s += p[(size_t)ch * 65536 + i4];
    ((f32x4*)raw)[i4] = s;
    float m = fmaxf(fmaxf(s[0], s[1]), fmaxf(s[2], s[3]));
    m = fmaxf(m, __shfl_xor(m, 1, 64));
    m = fmaxf(m, __shfl_xor(m, 2, 64));
    m = fmaxf(m, __shfl_xor(m, 4, 64));
    int r = i4 >> 3;
    float v = ((i4 & 7) == 0) ? (m / S[r >> 5]) : 0.f;  // divide after max: monotone-exact
    for (int o = 32; o > 0; o >>= 1) v += __shfl_down(v, o, 64);
    __shared__ float red[4];
    if ((threadIdx.x & 63) == 0) red[threadIdx.x >> 6] = v;
    __syncthreads();
    if (threadIdx.x == 0) atomicAdd(fam, red[0] + red[1] + red[2] + red[3]);
}

// ---------------- familiarity (atomic-fallback path only) --------------------
__global__ __launch_bounds__(256) void k_fam(const float* __restrict__ raw,
                                             const float* __restrict__ S,
                                             float* __restrict__ fam) {
    int r = blockIdx.x * 256 + threadIdx.x;            // 8192 rows
    const float4* ap = (const float4*)(raw + (size_t)r * N_);
    float m = -3.0e38f;
#pragma unroll
    for (int q = 0; q < 8; ++q) {
        float4 v = ap[q];
        m = fmaxf(m, fmaxf(fmaxf(v.x, v.y), fmaxf(v.z, v.w)));
    }
    m = m / S[r >> 5];
    for (int o = 32; o > 0; o >>= 1) m += __shfl_down(m, o, 64);
    __shared__ float red[4];
    if ((threadIdx.x & 63) == 0) red[threadIdx.x >> 6] = m;
    __syncthreads();
    if (threadIdx.x == 0) atomicAdd(fam, red[0] + red[1] + red[2] + red[3]);
}

// ---------------- Threefry-2x32-20 core (unchanged) ----------------
__device__ __forceinline__ uint32_t rotl32(uint32_t x, uint32_t r) {
    return (x << r) | (x >> (32u - r));
}
__device__ __forceinline__ void threefry(uint32_t k0, uint32_t k1,
                                         uint32_t x0, uint32_t x1,
                                         uint32_t& o0, uint32_t& o1) {
    uint32_t ks2 = k0 ^ k1 ^ 0x1BD11BDAu;
    x0 += k0; x1 += k1;
    x0 += x1; x1 = rotl32(x1, 13); x1 ^= x0;
    x0 += x1; x1 = rotl32(x1, 15); x1 ^= x0;
    x0 += x1; x1 = rotl32(x1, 26); x1 ^= x0;
    x0 += x1; x1 = rotl32(x1, 6);  x1 ^= x0;
    x0 += k1; x1 += ks2 + 1u;
    x0 += x1; x1 = rotl32(x1, 17); x1 ^= x0;
    x0 += x1; x1 = rotl32(x1, 29); x1 ^= x0;
    x0 += x1; x1 = rotl32(x1, 16); x1 ^= x0;
    x0 += x1; x1 = rotl32(x1, 24); x1 ^= x0;
    x0 += ks2; x1 += k0 + 2u;
    x0 += x1; x1 = rotl32(x1, 13); x1 ^= x0;
    x0 += x1; x1 = rotl32(x1, 15); x1 ^= x0;
    x0 += x1; x1 = rotl32(x1, 26); x1 ^= x0;
    x0 += x1; x1 = rotl32(x1, 6);  x1 ^= x0;
    x0 += k0; x1 += k1 + 3u;
    x0 += x1; x1 = rotl32(x1, 17); x1 ^= x0;
    x0 += x1; x1 = rotl32(x1, 29); x1 ^= x0;
    x0 += x1; x1 = rotl32(x1, 16); x1 ^= x0;
    x0 += x1; x1 = rotl32(x1, 24); x1 ^= x0;
    x0 += k1; x1 += ks2 + 4u;
    x0 += x1; x1 = rotl32(x1, 13); x1 ^= x0;
    x0 += x1; x1 = rotl32(x1, 15); x1 ^= x0;
    x0 += x1; x1 = rotl32(x1, 26); x1 ^= x0;
    x0 += x1; x1 = rotl32(x1, 6);  x1 ^= x0;
    x0 += ks2; x1 += k0 + 5u;
    o0 = x0; o1 = x1;
}

__device__ __forceinline__ float gumbel_of(uint32_t bits) {
    uint32_t fb = (bits >> 9) | 0x3F800000u;
    float f = __builtin_bit_cast(float, fb) - 1.0f;
    float u = f + 1.17549435e-38f;                     // == max(tiny, f*(1-tiny)+tiny)
    return -logf(-logf(u));
}

// ---------------- sample (unchanged: JAX partitionable threefry layout) ------
__global__ __launch_bounds__(256) void k_sample(const float* __restrict__ raw,
                                                const float* __restrict__ S,
                                                const float* __restrict__ fam,
                                                int* __restrict__ out) {
    int r0 = blockIdx.x * 256 + threadIdx.x;           // 0..4095
    int r1 = r0 + 4096;
    float avg  = fam[0] * (1.0f / 8192.0f);
    float temp = 1.0f / (avg + 1e-4f) - 1.0f;
    float sA = S[r0 >> 5], sB = S[r1 >> 5];
    const float* apA = raw + (size_t)r0 * N_;
    const float* apB = raw + (size_t)r1 * N_;

    float bestA = -3.4e38f, bestB = -3.4e38f;
    int biA = 0, biB = 0;
    for (int n = 0; n < 32; ++n) {
        uint32_t iA = (uint32_t)(r0 * 32 + n);
        uint32_t iB = (uint32_t)(r1 * 32 + n);
        uint32_t a0, a1, b0, b1;
        threefry(0u, 42u, 0u, iA, a0, a1);
        threefry(0u, 42u, 0u, iB, b0, b1);
        float vA = (apA[n] / sA) / temp + gumbel_of(a0 ^ a1);
        float vB = (apB[n] / sB) / temp + gumbel_of(b0 ^ b1);
        if (vA > bestA) { bestA = vA; biA = n; }
        if (vB > bestB) { bestB = vB; biB = n; }
    }
    int4* opA = (int4*)(out + (size_t)r0 * N_);
    int4* opB = (int4*)(out + (size_t)r1 * N_);
#pragma unroll
    for (int q = 0; q < 8; ++q) {
        int4 a, b;
        a.x = (q * 4 + 0) == biA; a.y = (q * 4 + 1) == biA;
        a.z = (q * 4 + 2) == biA; a.w = (q * 4 + 3) == biA;
        b.x = (q * 4 + 0) == biB; b.y = (q * 4 + 1) == biB;
        b.z = (q * 4 + 2) == biB; b.w = (q * 4 + 3) == biB;
        opA[q] = a; opB[q] = b;
    }
}

extern "C" void kernel_launch(void* const* d_in, const int* in_sizes, int n_in,
                              void* d_out, int out_size, void* d_ws, size_t ws_size,
                              hipStream_t stream) {
    const float* x    = (const float*)d_in[0];
    const int*   filt = (const int*)d_in[1];
    const float* w    = (const float*)d_in[2];
    int* out = (int*)d_out;

    char* ws = (char*)d_ws;
    float* raw  = (float*)ws;                          // 1 MB  (256*32*32 fp32)
    float* fam  = (float*)(ws + (1 << 20));            // 4 B
    float* S    = (float*)(ws + (1 << 20) + 128);      // 1 KB
    float* part = (float*)(ws + (2u << 20));           // 64 MB split-K partials

    const size_t need = (2u << 20) + (size_t)NCH * (BATCH * C_ * N_) * sizeof(float);
    const int use_part = (ws_size >= need) ? 1 : 0;

    if (use_part) {
        // fam zeroed by fused kernel (block 0, thread 0); S computed by blocks 0..255
        hipLaunchKernelGGL(k_fused,  dim3(768), dim3(256), 0, stream, x, filt, w, S, fam, part);
        hipLaunchKernelGGL(k_reduce, dim3(256), dim3(256), 0, stream, part, S, raw, fam);
        hipLaunchKernelGGL(k_sample, dim3(16),  dim3(256), 0, stream, raw, S, fam, out);
    } else {
        hipMemsetAsync(ws, 0, (1 << 20) + 128, stream);          // raw + fam (atomic path)
        hipLaunchKernelGGL(k_sum,    dim3(256), dim3(256), 0, stream, x, filt, S, fam);
        hipLaunchKernelGGL(k_gemm_fb, dim3(512), dim3(256), 0, stream, x, filt, w, raw);
        hipLaunchKernelGGL(k_fam,    dim3(32),  dim3(256), 0, stream, raw, S, fam);
        hipLaunchKernelGGL(k_sample, dim3(16),  dim3(256), 0, stream, raw, S, fam, out);
    }
}